// Round 4
// baseline (5245.398 us; speedup 1.0000x reference)
//
#include <hip/hip_runtime.h>

// PA_MSA bisect round 4: NO MFMA anywhere (VALU GEMM probe), sentinel-filled d_out,
// all static LDS <= 50KB, ws need ~49MB, per-batch host loop.
// B=4, C=384, H=W=128, heads=8, ch=48.

typedef unsigned short u16;
typedef __attribute__((ext_vector_type(8))) short s16x8;
typedef __attribute__((ext_vector_type(4))) float f32x4;

#define P_HW 16384
#define C_DIM 384

__device__ __forceinline__ u16 f2b(float f) {
  union { float f; unsigned u; } v; v.f = f;
  unsigned u = v.u;
  return (u16)((u + 0x7FFFu + ((u >> 16) & 1u)) >> 16);  // RNE
}
__device__ __forceinline__ float b2f(u16 h) {
  union { unsigned u; float f; } v; v.u = ((unsigned)h) << 16; return v.f;
}

// ---------- utility ----------
__global__ void fillf_k(float* __restrict__ p, float v, int n) {
  int i = blockIdx.x * 256 + threadIdx.x;
  if (i < n) p[i] = v;
}
__global__ void zerof_k(float* __restrict__ p, int n) {
  int i = blockIdx.x * 256 + threadIdx.x;
  if (i < n) p[i] = 0.f;
}

// fp32 NCHW (384,16384) -> bf16 NHWC (16384,384), one batch
__global__ __launch_bounds__(256) void tcvt_k(const float* __restrict__ in, u16* __restrict__ out) {
  const int tid = threadIdx.x;
  const int c0 = blockIdx.x * 32 + (tid & 3) * 8;
  const int p  = blockIdx.y * 64 + (tid >> 2);
  u16 tmp[8];
#pragma unroll
  for (int u = 0; u < 8; u++) tmp[u] = f2b(in[(size_t)(c0 + u) * P_HW + p]);
  *(s16x8*)(out + (size_t)p * C_DIM + c0) = *(s16x8*)tmp;
}

// ---------- VALU GEMM probe: out[o][p] = sum_c W[o][c] * Bact[p][c] ----------
// W fp32 [384][K] row-major (original input weights, no quantization).
// Bact NHWC bf16 [16384][384]; for K=768 chunk 0 reads B1, chunk 1 reads B2.
// mode 0: NHWC bf16 out; mode 2: NCHW bf16 out. Grid (256, 12), block 256.
__global__ __launch_bounds__(256) void vgemm_k(const float* __restrict__ Wf,
    const u16* __restrict__ B1, const u16* __restrict__ B2,
    u16* __restrict__ outp, int K, int mode) {
  __shared__ float lW[32 * 384];  // 49152 B
  const int tid = threadIdx.x;
  const int lane = tid & 63;      // p_local
  const int osub = tid >> 6;      // 0..3 (wave-uniform)
  const int p0 = blockIdx.x * 64;
  const int o0 = blockIdx.y * 32;
  const int p = p0 + lane;
  float acc[8] = {};
  for (int kc = 0; kc < K; kc += 384) {
    const u16* Bsrc = (kc == 0) ? B1 : B2;
    __syncthreads();
    for (int idx = tid * 4; idx < 32 * 384; idx += 1024) {
      int row = idx / 384, col = idx % 384;
      *(f32x4*)&lW[row * 384 + col] = *(const f32x4*)(Wf + (size_t)(o0 + row) * K + kc + col);
    }
    __syncthreads();
    for (int c = 0; c < 384; c += 8) {
      s16x8 bvec = *(const s16x8*)(Bsrc + (size_t)p * C_DIM + c);
      float bv[8];
#pragma unroll
      for (int u = 0; u < 8; u++) bv[u] = b2f((u16)bvec[u]);
#pragma unroll
      for (int oi = 0; oi < 8; oi++) {
        const float* wrow = &lW[(osub * 8 + oi) * 384 + c];  // wave-uniform -> LDS broadcast
        float a = acc[oi];
#pragma unroll
        for (int u = 0; u < 8; u++) a += wrow[u] * bv[u];
        acc[oi] = a;
      }
    }
  }
  if (mode == 0) {
    u16* d = outp + (size_t)p * C_DIM + o0 + osub * 8;
#pragma unroll
    for (int oi = 0; oi < 8; oi++) d[oi] = f2b(acc[oi]);
  } else {
#pragma unroll
    for (int oi = 0; oi < 8; oi++)
      outp[(size_t)(o0 + osub * 8 + oi) * P_HW + p] = f2b(acc[oi]);
  }
}

// ---------- depthwise 3x3, NHWC bf16 -> NHWC bf16 (one batch) ----------
__global__ __launch_bounds__(384) void dw_nhwc_k(const u16* __restrict__ in, u16* __restrict__ out,
                                                 const float* __restrict__ w) {
  const int c = threadIdx.x;
  const int y = blockIdx.x;
  float wr[9];
#pragma unroll
  for (int t = 0; t < 9; t++) wr[t] = w[c * 9 + t];
  const u16* base = in + c;
  u16* obase = out + c;
  auto ld = [&](int yy, int xx) -> float {
    if (yy < 0 || yy > 127 || xx < 0 || xx > 127) return 0.f;
    return b2f(base[((size_t)(yy * 128 + xx)) * C_DIM]);
  };
  float a0 = ld(y - 1, 0), a1 = ld(y, 0), a2 = ld(y + 1, 0);
  float p0 = 0.f, p1 = 0.f, p2 = 0.f;
  for (int x = 0; x < 128; x++) {
    float c0 = ld(y - 1, x + 1), c1 = ld(y, x + 1), c2 = ld(y + 1, x + 1);
    float acc = p0 * wr[0] + a0 * wr[1] + c0 * wr[2]
              + p1 * wr[3] + a1 * wr[4] + c1 * wr[5]
              + p2 * wr[6] + a2 * wr[7] + c2 * wr[8];
    obase[((size_t)(y * 128 + x)) * C_DIM] = f2b(acc);
    p0 = a0; p1 = a1; p2 = a2; a0 = c0; a1 = c1; a2 = c2;
  }
}

// ---------- depthwise 3x3, NCHW bf16 -> NCHW bf16 (one batch) ----------
__global__ __launch_bounds__(256) void dw_nchw_k(const u16* __restrict__ in, u16* __restrict__ out,
                                                 const float* __restrict__ w) {
  const int tid = threadIdx.x;
  const int x = tid & 127;
  const int y = blockIdx.x * 2 + (tid >> 7);
  const int c = blockIdx.y;
  float wr[9];
#pragma unroll
  for (int t = 0; t < 9; t++) wr[t] = w[c * 9 + t];
  const u16* base = in + (size_t)c * P_HW;
  float acc = 0.f;
#pragma unroll
  for (int ky = 0; ky < 3; ky++) {
    int yy = y + ky - 1;
    if (yy < 0 || yy > 127) continue;
#pragma unroll
    for (int kx = 0; kx < 3; kx++) {
      int xx = x + kx - 1;
      if (xx < 0 || xx > 127) continue;
      acc += b2f(base[yy * 128 + xx]) * wr[ky * 3 + kx];
    }
  }
  out[(size_t)c * P_HW + y * 128 + x] = f2b(acc);
}

// ---------- per-row sum of squares (one batch; z: 0=q,1=k) ----------
__global__ __launch_bounds__(256) void row_sumsq_k(const u16* __restrict__ q, const u16* __restrict__ k,
                                                   float* __restrict__ nq, float* __restrict__ nk) {
  const int c = blockIdx.x, t = blockIdx.z;
  const u16* src = (t == 0) ? q : k;
  float* dst = (t == 0) ? nq : nk;
  const u16* row = src + (size_t)c * P_HW;
  float s = 0.f;
  for (int i = threadIdx.x * 8; i < P_HW; i += 2048) {
    s16x8 v = *(const s16x8*)(row + i);
#pragma unroll
    for (int j = 0; j < 8; j++) { float f = b2f((u16)v[j]); s += f * f; }
  }
  __shared__ float red[256];
  red[threadIdx.x] = s;
  __syncthreads();
  for (int off = 128; off > 0; off >>= 1) {
    if (threadIdx.x < off) red[threadIdx.x] += red[threadIdx.x + off];
    __syncthreads();
  }
  if (threadIdx.x == 0) dst[c] = red[0];
}

// ---------- naive Gram (one batch): G[h][i][j] += sum_p q[i,p] k[j,p] ----------
// grid (9, 8, 8): bx = pair-group, by = h, bz = p-chunk.
__global__ __launch_bounds__(256) void gramn_k(const u16* __restrict__ q, const u16* __restrict__ k,
                                               float* __restrict__ G) {
  const int pair = blockIdx.x * 256 + threadIdx.x;  // [0, 2304)
  const int h = blockIdx.y;
  const int chunk = blockIdx.z;
  const int i = pair / 48, j = pair % 48;
  const u16* qrow = q + (size_t)(h * 48 + i) * P_HW;
  const u16* krow = k + (size_t)(h * 48 + j) * P_HW;
  const int p0 = chunk * 2048;
  float acc = 0.f;
  for (int p = p0; p < p0 + 2048; p += 8) {
    s16x8 qa = *(const s16x8*)(qrow + p);
    s16x8 ka = *(const s16x8*)(krow + p);
#pragma unroll
    for (int u = 0; u < 8; u++) acc += b2f((u16)qa[u]) * b2f((u16)ka[u]);
  }
  atomicAdd(&G[((size_t)h * 48 + i) * 48 + j], acc);
}

// ---------- softmax (one batch): fp32 attn out [8][48][48] ----------
__global__ void attn_softmax_k(const float* __restrict__ G, const float* __restrict__ nqA,
                               const float* __restrict__ nkA, const float* __restrict__ temp,
                               float* __restrict__ attnf) {
  const int h = blockIdx.x;
  const int i = threadIdx.x;
  __shared__ float mk[48];
  if (i < 48) mk[i] = fmaxf(sqrtf(nkA[h * 48 + i]), 1e-12f);
  __syncthreads();
  if (i < 48) {
    float mq = fmaxf(sqrtf(nqA[h * 48 + i]), 1e-12f);
    float T = temp[h];
    const float* g = G + ((size_t)h * 48 + i) * 48;
    float L[48];
    float mx = -1e30f;
    for (int j = 0; j < 48; j++) {
      L[j] = T * g[j] / (mq * mk[j]);
      mx = fmaxf(mx, L[j]);
    }
    float sum = 0.f;
    for (int j = 0; j < 48; j++) { L[j] = expf(L[j] - mx); sum += L[j]; }
    float inv = 1.f / sum;
    float* d = attnf + ((size_t)h * 48 + i) * 48;
    for (int j = 0; j < 48; j++) d[j] = L[j] * inv;
  }
}

// ---------- naive AV (one batch): out[h*48+i][p] = sum_j attn[h][i][j] v[p][h*48+j] ----------
// grid (64), block 256; per-head LDS staging (9216 B).
__global__ __launch_bounds__(256) void avn_k(const float* __restrict__ attnf, const u16* __restrict__ v,
                                             float* __restrict__ out) {
  __shared__ float la[2304];
  const int tid = threadIdx.x;
  const int p = blockIdx.x * 256 + tid;
  const u16* vp = v + (size_t)p * C_DIM;
  for (int h = 0; h < 8; h++) {
    __syncthreads();
    for (int idx = tid; idx < 2304; idx += 256) la[idx] = attnf[h * 2304 + idx];
    __syncthreads();
    float vf[48];
#pragma unroll
    for (int s = 0; s < 6; s++) {
      s16x8 t8 = *(const s16x8*)(vp + h * 48 + s * 8);
#pragma unroll
      for (int u = 0; u < 8; u++) vf[s * 8 + u] = b2f((u16)t8[u]);
    }
    for (int i = 0; i < 48; i++) {
      const float* row = &la[i * 48];
      float acc = 0.f;
#pragma unroll
      for (int j = 0; j < 48; j += 4) {
        acc += row[j] * vf[j] + row[j + 1] * vf[j + 1] + row[j + 2] * vf[j + 2] + row[j + 3] * vf[j + 3];
      }
      out[(size_t)(h * 48 + i) * P_HW + p] = acc;
    }
  }
}

// ---------- launch ----------
extern "C" void kernel_launch(void* const* d_in, const int* in_sizes, int n_in,
                              void* d_out, int out_size, void* d_ws, size_t ws_size,
                              hipStream_t stream) {
  const float* x      = (const float*)d_in[0];
  const float* t      = (const float*)d_in[1];
  const float* w_q    = (const float*)d_in[2];
  const float* w_q_dw = (const float*)d_in[3];
  const float* w_qT   = (const float*)d_in[4];
  const float* w_qT_dw= (const float*)d_in[5];
  const float* w_qcat = (const float*)d_in[6];
  const float* w_k    = (const float*)d_in[7];
  const float* w_k_dw = (const float*)d_in[8];
  const float* w_v    = (const float*)d_in[9];
  const float* w_v_dw = (const float*)d_in[10];
  const float* temp   = (const float*)d_in[11];
  float* out = (float*)d_out;

  // ws: G[32*2304] nq[1536] nk[1536] attnf[32*2304] then 4 bf16 buffers (12.58MB each)
  float* G     = (float*)d_ws;
  float* nq    = G + 73728;
  float* nk    = nq + 1536;
  float* attnf = nk + 1536;
  u16* bufs = (u16*)(attnf + 73728);        // byte offset 602112, 16B-aligned
  const size_t BUFE = (size_t)P_HW * C_DIM; // 6,291,456 elems
  u16* A = bufs;
  u16* Bb = A + BUFE;
  u16* Cb = Bb + BUFE;
  u16* Db = Cb + BUFE;

  // sentinel-fill d_out (3.0) — unwritten regions become absmax ~3 diagnostics
  fillf_k<<<98304, 256, 0, stream>>>(out, 3.0f, 25165824);
  zerof_k<<<288, 256, 0, stream>>>(G, 73728);

  for (int b = 0; b < 4; b++) {
    const float* xb = x + (size_t)b * C_DIM * P_HW;
    const float* tb = t + (size_t)b * C_DIM * P_HW;
    float* outb = out + (size_t)b * C_DIM * P_HW;
    u16* O = (u16*)outb;                    // batch-local scratch inside own out region
    float* Gb = G + (size_t)b * 8 * 2304;
    float* nqb = nq + (size_t)b * C_DIM;
    float* nkb = nk + (size_t)b * C_DIM;
    float* attnb = attnf + (size_t)b * 8 * 2304;

    tcvt_k<<<dim3(12, 256), 256, 0, stream>>>(tb, A);                       // t -> A (NHWC)
    vgemm_k<<<dim3(256, 12), 256, 0, stream>>>(w_qT, A, A, Bb, 384, 0);     // qT -> B
    dw_nhwc_k<<<128, 384, 0, stream>>>(Bb, A, w_qT_dw);                     // qtd -> A
    tcvt_k<<<dim3(12, 256), 256, 0, stream>>>(xb, Bb);                      // x -> B
    vgemm_k<<<dim3(256, 12), 256, 0, stream>>>(w_k, Bb, Bb, Cb, 384, 2);    // k (NCHW) -> C
    dw_nchw_k<<<dim3(64, 384), 256, 0, stream>>>(Cb, Db, w_k_dw);           // kd -> D
    vgemm_k<<<dim3(256, 12), 256, 0, stream>>>(w_q, Bb, Bb, Cb, 384, 0);    // q -> C
    dw_nhwc_k<<<128, 384, 0, stream>>>(Cb, O, w_q_dw);                      // qd -> O
    vgemm_k<<<dim3(256, 12), 256, 0, stream>>>(w_v, Bb, Bb, Cb, 384, 0);    // v -> C
    dw_nhwc_k<<<128, 384, 0, stream>>>(Cb, Bb, w_v_dw);                     // vd -> B
    vgemm_k<<<dim3(256, 12), 256, 0, stream>>>(w_qcat, O, A, Cb, 768, 2);   // qf (NCHW) -> C
    row_sumsq_k<<<dim3(384, 1, 2), 256, 0, stream>>>(Cb, Db, nqb, nkb);
    gramn_k<<<dim3(9, 8, 8), 256, 0, stream>>>(Cb, Db, Gb);
    attn_softmax_k<<<8, 64, 0, stream>>>(Gb, nqb, nkb, temp, attnb);
    avn_k<<<64, 256, 0, stream>>>(attnb, Bb, outb);
  }
}